// Round 1
// baseline (444.229 us; speedup 1.0000x reference)
//
#include <hip/hip_runtime.h>
#include <hip/hip_bf16.h>

typedef __attribute__((ext_vector_type(8))) __bf16 bf16x8;
typedef __attribute__((ext_vector_type(4))) float f32x4;

#define BATCH 16
#define LSEQ 2048
#define DIM 128
#define EPITCH 2056   // bf16 elems per LDS row: 2048 + 8 pad (keeps 16B align)

__device__ __forceinline__ bf16x8 cvt8(float4 a, float4 b) {
    bf16x8 r;
    r[0] = (__bf16)a.x; r[1] = (__bf16)a.y; r[2] = (__bf16)a.z; r[3] = (__bf16)a.w;
    r[4] = (__bf16)b.x; r[5] = (__bf16)b.y; r[6] = (__bf16)b.z; r[7] = (__bf16)b.w;
    return r;
}

__global__ __launch_bounds__(256, 2)
void sdpa_fused(const float* __restrict__ qg,
                const float* __restrict__ kg,
                const float* __restrict__ vg,
                const int*   __restrict__ maskg,
                float* __restrict__ og,
                float* __restrict__ wg)
{
    __shared__ __align__(16) __bf16 Es[16 * EPITCH];   // 65792 B, unnormalized exp(scores) in bf16
    __shared__ float Osum[16 * DIM];                   // 8192 B
    __shared__ float rowpart[4][16];
    __shared__ float rowinv[16];

    const int tid  = threadIdx.x;
    const int wave = tid >> 6;
    const int lane = tid & 63;
    const int g    = lane >> 4;    // lane group 0..3
    const int li   = lane & 15;

    const int qt = blockIdx.x;     // 0..127  (query tile)
    const int b  = blockIdx.y;     // 0..15   (batch)
    const int q0 = qt * 16;

    // zero O accumulator
    for (int i = tid; i < 16 * DIM; i += 256) Osum[i] = 0.0f;

    // ---- Q fragments: lane holds Q[q0+li][dstep*32 + g*8 + j], scale*log2(e) folded in.
    const float qscale = 0.08838834764831845f * 1.4426950408889634f; // 1/sqrt(128) * log2(e)
    bf16x8 qf[4];
    {
        const float* qrow = qg + ((size_t)b * LSEQ + q0 + li) * DIM + g * 8;
        #pragma unroll
        for (int dstep = 0; dstep < 4; ++dstep) {
            const float4* p4 = reinterpret_cast<const float4*>(qrow + dstep * 32);
            float4 x = p4[0];
            float4 y = p4[1];
            x.x *= qscale; x.y *= qscale; x.z *= qscale; x.w *= qscale;
            y.x *= qscale; y.y *= qscale; y.z *= qscale; y.w *= qscale;
            qf[dstep] = cvt8(x, y);
        }
    }

    float rsum[4] = {0.f, 0.f, 0.f, 0.f};   // per-lane partials for rows g*4+r over cols == li (mod 16)
    f32x4 accO[8];
    #pragma unroll
    for (int i = 0; i < 8; ++i) accO[i] = (f32x4){0.f, 0.f, 0.f, 0.f};

    const int kwave0 = wave * 512;

    for (int it = 0; it < 16; ++it) {
        const int kb = kwave0 + it * 32;

        // ---- QK^T: S block 16q x 32k (two 16x16 col tiles), log2-domain scores
        f32x4 s0 = (f32x4){0.f, 0.f, 0.f, 0.f};
        f32x4 s1 = (f32x4){0.f, 0.f, 0.f, 0.f};
        {
            const float* kp0 = kg + ((size_t)b * LSEQ + kb + li) * DIM + g * 8;
            const float* kp1 = kp0 + (size_t)16 * DIM;
            #pragma unroll
            for (int dstep = 0; dstep < 4; ++dstep) {
                const float4* a4 = reinterpret_cast<const float4*>(kp0 + dstep * 32);
                const float4* b4 = reinterpret_cast<const float4*>(kp1 + dstep * 32);
                bf16x8 kf0 = cvt8(a4[0], a4[1]);
                bf16x8 kf1 = cvt8(b4[0], b4[1]);
                s0 = __builtin_amdgcn_mfma_f32_16x16x32_bf16(qf[dstep], kf0, s0, 0, 0, 0);
                s1 = __builtin_amdgcn_mfma_f32_16x16x32_bf16(qf[dstep], kf1, s1, 0, 0, 0);
            }
        }

        // ---- mask + exp2 + store E (bf16) + row-sum.  D layout: col=li(key), row=g*4+r(query)
        {
            const int* mbase = maskg + ((size_t)b * LSEQ + q0) * LSEQ + kb + li;
            #pragma unroll
            for (int t = 0; t < 2; ++t) {
                f32x4 sv = t ? s1 : s0;
                const int col = kb + t * 16 + li;
                #pragma unroll
                for (int r = 0; r < 4; ++r) {
                    const int row = g * 4 + r;
                    const int m = mbase[(size_t)row * LSEQ + t * 16];
                    float sc = m ? -1.0e9f : sv[r];          // mask==true -> NEG_INF
                    float ev = __builtin_amdgcn_exp2f(sc);   // masked -> exactly 0
                    rsum[r] += ev;
                    Es[row * EPITCH + col] = (__bf16)ev;
                }
            }
        }

        // ---- PV: O += E(16x32,bf16) * V(32x128,bf16)
        {
            // A frag: row=li(query), k = keys kb + g*8 + j  (same-wave LDS, in-order DS ops)
            bf16x8 af = *reinterpret_cast<const bf16x8*>(&Es[li * EPITCH + kb + g * 8]);
            const float* vbase = vg + ((size_t)b * LSEQ + kb + g * 8) * DIM + li;
            #pragma unroll
            for (int dt = 0; dt < 8; ++dt) {
                const float* vp = vbase + dt * 16;
                bf16x8 bf;
                #pragma unroll
                for (int j = 0; j < 8; ++j) bf[j] = (__bf16)vp[(size_t)j * DIM];
                accO[dt] = __builtin_amdgcn_mfma_f32_16x16x32_bf16(af, bf, accO[dt], 0, 0, 0);
            }
        }
    }

    // ---- reduce row sums across the 16 li lanes (stays within lane group)
    #pragma unroll
    for (int off = 1; off < 16; off <<= 1) {
        #pragma unroll
        for (int r = 0; r < 4; ++r) rsum[r] += __shfl_xor(rsum[r], off, 64);
    }
    if (li == 0) {
        #pragma unroll
        for (int r = 0; r < 4; ++r) rowpart[wave][g * 4 + r] = rsum[r];
    }
    __syncthreads();   // E complete, rowpart complete, Osum zero-init complete

    // ---- combine O partials across waves
    #pragma unroll
    for (int dt = 0; dt < 8; ++dt) {
        #pragma unroll
        for (int r = 0; r < 4; ++r)
            atomicAdd(&Osum[(g * 4 + r) * DIM + dt * 16 + li], accO[dt][r]);
    }
    if (tid < 16) {
        float s = rowpart[0][tid] + rowpart[1][tid] + rowpart[2][tid] + rowpart[3][tid];
        rowinv[tid] = 1.0f / s;
    }
    __syncthreads();

    // ---- write W = E * rowinv  (coalesced float4)
    const size_t wbase = ((size_t)b * LSEQ + q0) * LSEQ;
    for (int i = tid; i < 16 * (LSEQ / 4); i += 256) {
        const int idx4 = i * 4;
        const int row = idx4 >> 11;          // /2048
        const int col = idx4 & 2047;
        const __bf16* ep = &Es[row * EPITCH + col];
        const float inv = rowinv[row];
        float4 wv;
        wv.x = (float)ep[0] * inv;
        wv.y = (float)ep[1] * inv;
        wv.z = (float)ep[2] * inv;
        wv.w = (float)ep[3] * inv;
        *reinterpret_cast<float4*>(wg + wbase + (size_t)row * LSEQ + col) = wv;
    }

    // ---- write O = Osum * rowinv
    const size_t obase = ((size_t)b * LSEQ + q0) * DIM;
    for (int i = tid; i < 16 * DIM; i += 256) {
        const int row = i >> 7;              // /128
        og[obase + i] = Osum[i] * rowinv[row];
    }
}

extern "C" void kernel_launch(void* const* d_in, const int* in_sizes, int n_in,
                              void* d_out, int out_size, void* d_ws, size_t ws_size,
                              hipStream_t stream) {
    const float* q    = (const float*)d_in[0];
    const float* k    = (const float*)d_in[1];
    const float* v    = (const float*)d_in[2];
    const int*   mask = (const int*)d_in[3];
    float* o = (float*)d_out;                                   // (16,2048,128)
    float* w = (float*)d_out + (size_t)BATCH * LSEQ * DIM;      // (16,2048,2048)
    dim3 grid(LSEQ / 16, BATCH);
    sdpa_fused<<<grid, 256, 0, stream>>>(q, k, v, mask, o, w);
}

// Round 2
// 402.376 us; speedup vs baseline: 1.1040x; 1.1040x over previous
//
#include <hip/hip_runtime.h>
#include <hip/hip_bf16.h>

typedef __attribute__((ext_vector_type(8))) __bf16 bf16x8;
typedef __attribute__((ext_vector_type(4))) float f32x4;

#define BATCH 16
#define LSEQ 2048
#define DIM 128
#define EPITCH 2056   // bf16 elems per LDS row: 2048 + 8 pad

__device__ __forceinline__ bf16x8 cvt8(float4 a, float4 b) {
    bf16x8 r;
    r[0] = (__bf16)a.x; r[1] = (__bf16)a.y; r[2] = (__bf16)a.z; r[3] = (__bf16)a.w;
    r[4] = (__bf16)b.x; r[5] = (__bf16)b.y; r[6] = (__bf16)b.z; r[7] = (__bf16)b.w;
    return r;
}

// ---------------- preproc: K -> bf16 (same layout) ----------------
__global__ __launch_bounds__(256)
void cast_k_kernel(const float* __restrict__ in, __bf16* __restrict__ out) {
    size_t i = ((size_t)blockIdx.x * 256 + threadIdx.x) * 8;
    const float4* p = reinterpret_cast<const float4*>(in + i);
    *reinterpret_cast<bf16x8*>(out + i) = cvt8(p[0], p[1]);
}

// ---------------- preproc: V -> bf16 transposed Vt[b][d][k] ----------------
__global__ __launch_bounds__(256)
void transpose_v_kernel(const float* __restrict__ v, __bf16* __restrict__ vt) {
    __shared__ __bf16 t[32][DIM + 8];
    const int b = blockIdx.y, k0 = blockIdx.x * 32;
    const int tid = threadIdx.x;
    {   // load 32 keys x 128 dims, coalesced float4
        const int r = tid >> 3, c8 = tid & 7;
        const float* src = v + ((size_t)b * LSEQ + k0 + r) * DIM;
        #pragma unroll
        for (int j = 0; j < 4; ++j) {
            const int c = (c8 + 8 * j) * 4;
            float4 x = *reinterpret_cast<const float4*>(src + c);
            t[r][c + 0] = (__bf16)x.x; t[r][c + 1] = (__bf16)x.y;
            t[r][c + 2] = (__bf16)x.z; t[r][c + 3] = (__bf16)x.w;
        }
    }
    __syncthreads();
    {   // write transposed: 128 d-rows x 32 k
        const int d = tid >> 1, ho = (tid & 1) * 16;
        __bf16* dst = vt + ((size_t)b * DIM + d) * LSEQ + k0 + ho;
        bf16x8 w0, w1;
        #pragma unroll
        for (int j = 0; j < 8; ++j) { w0[j] = t[ho + j][d]; w1[j] = t[ho + 8 + j][d]; }
        *reinterpret_cast<bf16x8*>(dst) = w0;
        *reinterpret_cast<bf16x8*>(dst + 8) = w1;
    }
}

// ---------------- helpers for the fused kernel ----------------
__device__ __forceinline__ void load_mask8(const int* __restrict__ mrow, int it, int g, int* m) {
    const int* p = mrow + it * 32;
    #pragma unroll
    for (int t = 0; t < 2; ++t)
        #pragma unroll
        for (int r = 0; r < 4; ++r)
            m[t * 4 + r] = p[(size_t)(g * 4 + r) * LSEQ + t * 16];
}

__device__ __forceinline__ void load_k_pre(const __bf16* __restrict__ kbf, size_t browbase,
                                           int kb, int li, int g, bf16x8* kf) {
    const __bf16* p0 = kbf + (browbase + kb + li) * DIM + g * 8;
    #pragma unroll
    for (int t = 0; t < 2; ++t)
        #pragma unroll
        for (int d = 0; d < 4; ++d)
            kf[t * 4 + d] = *reinterpret_cast<const bf16x8*>(p0 + (size_t)t * 16 * DIM + d * 32);
}

__device__ __forceinline__ void load_k_f32(const float* __restrict__ kg, size_t browbase,
                                           int kb, int li, int g, bf16x8* kf) {
    const float* p0 = kg + (browbase + kb + li) * DIM + g * 8;
    #pragma unroll
    for (int t = 0; t < 2; ++t)
        #pragma unroll
        for (int d = 0; d < 4; ++d) {
            const float4* p4 = reinterpret_cast<const float4*>(p0 + (size_t)t * 16 * DIM + d * 32);
            kf[t * 4 + d] = cvt8(p4[0], p4[1]);
        }
}

template<bool PRE>
__global__ __launch_bounds__(256, 2)
void sdpa_fused(const float* __restrict__ qg,
                const float* __restrict__ kg,
                const float* __restrict__ vg,
                const __bf16* __restrict__ kbf,
                const __bf16* __restrict__ vtb,
                const int*   __restrict__ maskg,
                float* __restrict__ og,
                float* __restrict__ wg)
{
    __shared__ __align__(16) __bf16 Es[16 * EPITCH];
    __shared__ float Osum[16 * DIM];
    __shared__ float rowpart[4][16];
    __shared__ float rowinv[16];

    const int tid  = threadIdx.x;
    const int wave = tid >> 6;
    const int lane = tid & 63;
    const int g    = lane >> 4;
    const int li   = lane & 15;

    const int qt = blockIdx.x;
    const int b  = blockIdx.y;
    const int q0 = qt * 16;

    for (int i = tid; i < 16 * DIM; i += 256) Osum[i] = 0.0f;

    // Q fragments with scale * log2(e) folded in
    const float qscale = 0.08838834764831845f * 1.4426950408889634f;
    bf16x8 qf[4];
    {
        const float* qrow = qg + ((size_t)b * LSEQ + q0 + li) * DIM + g * 8;
        #pragma unroll
        for (int d = 0; d < 4; ++d) {
            const float4* p4 = reinterpret_cast<const float4*>(qrow + d * 32);
            float4 x = p4[0];
            float4 y = p4[1];
            x.x *= qscale; x.y *= qscale; x.z *= qscale; x.w *= qscale;
            y.x *= qscale; y.y *= qscale; y.z *= qscale; y.w *= qscale;
            qf[d] = cvt8(x, y);
        }
    }

    float rsum[4] = {0.f, 0.f, 0.f, 0.f};
    f32x4 accO[8];
    #pragma unroll
    for (int i = 0; i < 8; ++i) accO[i] = (f32x4){0.f, 0.f, 0.f, 0.f};

    const int kwave0 = wave * 512;
    const size_t browbase = (size_t)b * LSEQ;
    const int* mrow = maskg + (browbase + q0) * LSEQ + kwave0 + li;

    // pipeline registers: mask 2-deep, K 1-deep
    int mc[8], mn[8];
    bf16x8 kc[8];

    load_mask8(mrow, 0, g, mc);
    load_mask8(mrow, 1, g, mn);
    if (PRE) load_k_pre(kbf, browbase, kwave0, li, g, kc);
    else     load_k_f32(kg,  browbase, kwave0, li, g, kc);

    for (int it = 0; it < 16; ++it) {
        const int kb = kwave0 + it * 32;

        // ---- issue V loads for this iteration (consumed at the end of the body)
        bf16x8 vc[8];
        if (PRE) {
            const __bf16* vp = vtb + ((size_t)b * DIM + li) * LSEQ + kb + g * 8;
            #pragma unroll
            for (int dt = 0; dt < 8; ++dt)
                vc[dt] = *reinterpret_cast<const bf16x8*>(vp + (size_t)dt * 16 * LSEQ);
        }

        // ---- QK^T with prefetched K fragments
        f32x4 s0 = (f32x4){0.f, 0.f, 0.f, 0.f};
        f32x4 s1 = (f32x4){0.f, 0.f, 0.f, 0.f};
        #pragma unroll
        for (int d = 0; d < 4; ++d) {
            s0 = __builtin_amdgcn_mfma_f32_16x16x32_bf16(qf[d], kc[d],     s0, 0, 0, 0);
            s1 = __builtin_amdgcn_mfma_f32_16x16x32_bf16(qf[d], kc[4 + d], s1, 0, 0, 0);
        }

        // ---- prefetch K for it+1
        if (it + 1 < 16) {
            if (PRE) load_k_pre(kbf, browbase, kb + 32, li, g, kc);
            else     load_k_f32(kg,  browbase, kb + 32, li, g, kc);
        }

        // ---- mask + exp2 + E store + row sums (mask prefetched 2 deep)
        #pragma unroll
        for (int t = 0; t < 2; ++t) {
            f32x4 sv = t ? s1 : s0;
            const int col = kb + t * 16 + li;
            #pragma unroll
            for (int r = 0; r < 4; ++r) {
                float sc = mc[t * 4 + r] ? -1.0e9f : sv[r];
                float ev = __builtin_amdgcn_exp2f(sc);
                rsum[r] += ev;
                Es[(g * 4 + r) * EPITCH + col] = (__bf16)ev;
            }
        }
        #pragma unroll
        for (int i = 0; i < 8; ++i) mc[i] = mn[i];
        if (it + 2 < 16) load_mask8(mrow, it + 2, g, mn);

        // ---- PV: A-frag from LDS (same-wave, in-order DS), B from Vt / fallback
        bf16x8 af = *reinterpret_cast<const bf16x8*>(&Es[li * EPITCH + kb + g * 8]);
        if (PRE) {
            #pragma unroll
            for (int dt = 0; dt < 8; ++dt)
                accO[dt] = __builtin_amdgcn_mfma_f32_16x16x32_bf16(af, vc[dt], accO[dt], 0, 0, 0);
        } else {
            const float* vbase = vg + (browbase + kb + g * 8) * DIM + li;
            #pragma unroll
            for (int dt = 0; dt < 8; ++dt) {
                const float* vp = vbase + dt * 16;
                bf16x8 bf;
                #pragma unroll
                for (int j = 0; j < 8; ++j) bf[j] = (__bf16)vp[(size_t)j * DIM];
                accO[dt] = __builtin_amdgcn_mfma_f32_16x16x32_bf16(af, bf, accO[dt], 0, 0, 0);
            }
        }
    }

    // ---- row-sum reduce across the 16 li lanes
    #pragma unroll
    for (int off = 1; off < 16; off <<= 1) {
        #pragma unroll
        for (int r = 0; r < 4; ++r) rsum[r] += __shfl_xor(rsum[r], off, 64);
    }
    if (li == 0) {
        #pragma unroll
        for (int r = 0; r < 4; ++r) rowpart[wave][g * 4 + r] = rsum[r];
    }
    __syncthreads();

    // ---- combine O partials across waves
    #pragma unroll
    for (int dt = 0; dt < 8; ++dt) {
        #pragma unroll
        for (int r = 0; r < 4; ++r)
            atomicAdd(&Osum[(g * 4 + r) * DIM + dt * 16 + li], accO[dt][r]);
    }
    if (tid < 16) {
        float s = rowpart[0][tid] + rowpart[1][tid] + rowpart[2][tid] + rowpart[3][tid];
        rowinv[tid] = 1.0f / s;
    }
    __syncthreads();

    // ---- write W = E * rowinv (coalesced float4)
    const size_t wbase = (browbase + q0) * LSEQ;
    for (int i = tid; i < 16 * (LSEQ / 4); i += 256) {
        const int idx4 = i * 4;
        const int row = idx4 >> 11;
        const int col = idx4 & 2047;
        const __bf16* ep = &Es[row * EPITCH + col];
        const float inv = rowinv[row];
        float4 wv;
        wv.x = (float)ep[0] * inv;
        wv.y = (float)ep[1] * inv;
        wv.z = (float)ep[2] * inv;
        wv.w = (float)ep[3] * inv;
        *reinterpret_cast<float4*>(wg + wbase + (size_t)row * LSEQ + col) = wv;
    }

    // ---- write O = Osum * rowinv
    const size_t obase = (browbase + q0) * DIM;
    for (int i = tid; i < 16 * DIM; i += 256) {
        const int row = i >> 7;
        og[obase + i] = Osum[i] * rowinv[row];
    }
}

extern "C" void kernel_launch(void* const* d_in, const int* in_sizes, int n_in,
                              void* d_out, int out_size, void* d_ws, size_t ws_size,
                              hipStream_t stream) {
    const float* q    = (const float*)d_in[0];
    const float* k    = (const float*)d_in[1];
    const float* v    = (const float*)d_in[2];
    const int*   mask = (const int*)d_in[3];
    float* o = (float*)d_out;
    float* w = (float*)d_out + (size_t)BATCH * LSEQ * DIM;

    const size_t nKV  = (size_t)BATCH * LSEQ * DIM;       // 4.19M elems
    const size_t need = 2 * nKV * sizeof(__bf16);         // 16 MB

    dim3 grid(LSEQ / 16, BATCH);
    if (ws_size >= need) {
        __bf16* kbf = (__bf16*)d_ws;
        __bf16* vt  = kbf + nKV;
        cast_k_kernel<<<nKV / 2048, 256, 0, stream>>>(k, kbf);
        transpose_v_kernel<<<dim3(LSEQ / 32, BATCH), 256, 0, stream>>>(v, vt);
        sdpa_fused<true><<<grid, 256, 0, stream>>>(q, k, v, kbf, vt, mask, o, w);
    } else {
        sdpa_fused<false><<<grid, 256, 0, stream>>>(q, k, v, nullptr, nullptr, mask, o, w);
    }
}